// Round 1
// baseline (904.245 us; speedup 1.0000x reference)
//
#include <hip/hip_runtime.h>

#define NS   32
#define NC   16
#define NSCD 48
#define TT   128
#define NBATCH 64

// ---------------------------------------------------------------------------
// closed-form 4x4 inverse via 2x2 blocks (SPD-safe, no pivoting needed)
// ---------------------------------------------------------------------------
__device__ __forceinline__ void inv4(const float P[4][4], float IP[4][4]) {
    float a00=P[0][0], a01=P[0][1], a10=P[1][0], a11=P[1][1];
    float b00=P[0][2], b01=P[0][3], b10=P[1][2], b11=P[1][3];
    float c00=P[2][0], c01=P[2][1], c10=P[3][0], c11=P[3][1];
    float d00=P[2][2], d01=P[2][3], d10=P[3][2], d11=P[3][3];
    float r = 1.0f / (a00*a11 - a01*a10);
    float ia00 =  a11*r, ia01 = -a01*r, ia10 = -a10*r, ia11 = a00*r;
    float t00 = ia00*b00 + ia01*b10, t01 = ia00*b01 + ia01*b11;
    float t10 = ia10*b00 + ia11*b10, t11 = ia10*b01 + ia11*b11;
    float u00 = c00*ia00 + c01*ia10, u01 = c00*ia01 + c01*ia11;
    float u10 = c10*ia00 + c11*ia10, u11 = c10*ia01 + c11*ia11;
    float s00 = d00 - (c00*t00 + c01*t10), s01 = d01 - (c00*t01 + c01*t11);
    float s10 = d10 - (c10*t00 + c11*t10), s11 = d11 - (c10*t01 + c11*t11);
    float rs = 1.0f / (s00*s11 - s01*s10);
    float is00 =  s11*rs, is01 = -s01*rs, is10 = -s10*rs, is11 = s00*rs;
    float su00 = is00*u00 + is01*u10, su01 = is00*u01 + is01*u11;
    float su10 = is10*u00 + is11*u10, su11 = is10*u01 + is11*u11;
    IP[0][0] = ia00 + (t00*su00 + t01*su10);
    IP[0][1] = ia01 + (t00*su01 + t01*su11);
    IP[1][0] = ia10 + (t10*su00 + t11*su10);
    IP[1][1] = ia11 + (t10*su01 + t11*su11);
    IP[0][2] = -(t00*is00 + t01*is10);  IP[0][3] = -(t00*is01 + t01*is11);
    IP[1][2] = -(t10*is00 + t11*is10);  IP[1][3] = -(t10*is01 + t11*is11);
    IP[2][0] = -su00; IP[2][1] = -su01;
    IP[3][0] = -su10; IP[3][1] = -su11;
    IP[2][2] = is00;  IP[2][3] = is01;
    IP[3][2] = is10;  IP[3][3] = is11;
}

// ---------------------------------------------------------------------------
// Kernel A: backward Riccati recursion. One block (512 thr) per batch.
// Stores KT[32][16] followed by k[16] (528 floats) per (b,t) into ws.
// ---------------------------------------------------------------------------
__global__ __launch_bounds__(512, 1)
void lqr_backward(const float* __restrict__ Q, const float* __restrict__ p,
                  const float* __restrict__ A, const float* __restrict__ Bm,
                  const float* __restrict__ c1, float* __restrict__ Kws)
{
    const int b   = blockIdx.x;
    const int tid = threadIdx.x;

    __shared__ __align__(16) float Fs[32*48];   // F = [A | Bm], row-major
    __shared__ __align__(16) float Vs[32*32];   // V (exactly symmetric)
    __shared__ __align__(16) float Ms[32*48];   // M = V F ; reused as V-tmp
    __shared__ __align__(16) float Qt[48*48];   // working Qt
    __shared__ __align__(16) float Wa[16*52];   // solve ping
    __shared__ __align__(16) float Wb[16*52];   // solve pong
    __shared__ __align__(16) float KK[16*52];   // Quu^{-1}[Qux|qu]
    __shared__ __align__(16) float qts[64];
    __shared__ float vsv[32], fts[32], wv[32];
    __shared__ float invPs[4*16];

    // ---- load F, ft; zero V, v
    for (int s = tid; s < 256; s += 512) {
        int k = s >> 3, q = s & 7;
        ((float4*)Fs)[k*12 + q] = ((const float4*)A)[(b*32 + k)*8 + q];
    }
    for (int s = tid; s < 128; s += 512) {
        int k = s >> 2, q = s & 3;
        ((float4*)Fs)[k*12 + 8 + q] = ((const float4*)Bm)[(b*32 + k)*4 + q];
    }
    for (int s = tid; s < 256; s += 512) ((float4*)Vs)[s] = make_float4(0,0,0,0);
    if (tid < 32) { vsv[tid] = 0.0f; fts[tid] = c1[b*32 + tid]; }
    __syncthreads();

    for (int t = TT-1; t >= 0; --t) {
        const float* Qsrc = Q + (size_t)(b*TT + t) * 2304;
        const float* psrc = p + (size_t)(b*TT + t) * 48;

        // ---- P0: M = V F (threads 0..95), w = V ft + v (96..127),
        //          load Qt/p from global (128..511)
        if (tid < 96) {
            int i0 = (tid/12)*4, j0q = tid % 12;
            float a00=0,a01=0,a02=0,a03=0, a10=0,a11=0,a12=0,a13=0;
            float a20=0,a21=0,a22=0,a23=0, a30=0,a31=0,a32=0,a33=0;
            #pragma unroll
            for (int k = 0; k < 32; ++k) {
                float4 vv = ((float4*)Vs)[k*8 + (i0>>2)];   // V[k][i0..i0+3]
                float4 ff = ((float4*)Fs)[k*12 + j0q];       // F[k][j0..j0+3]
                a00 += vv.x*ff.x; a01 += vv.x*ff.y; a02 += vv.x*ff.z; a03 += vv.x*ff.w;
                a10 += vv.y*ff.x; a11 += vv.y*ff.y; a12 += vv.y*ff.z; a13 += vv.y*ff.w;
                a20 += vv.z*ff.x; a21 += vv.z*ff.y; a22 += vv.z*ff.z; a23 += vv.z*ff.w;
                a30 += vv.w*ff.x; a31 += vv.w*ff.y; a32 += vv.w*ff.z; a33 += vv.w*ff.w;
            }
            ((float4*)Ms)[(i0+0)*12 + j0q] = make_float4(a00,a01,a02,a03);
            ((float4*)Ms)[(i0+1)*12 + j0q] = make_float4(a10,a11,a12,a13);
            ((float4*)Ms)[(i0+2)*12 + j0q] = make_float4(a20,a21,a22,a23);
            ((float4*)Ms)[(i0+3)*12 + j0q] = make_float4(a30,a31,a32,a33);
        } else if (tid < 128) {
            int i = tid - 96;
            float acc = vsv[i];
            #pragma unroll
            for (int k = 0; k < 32; ++k) acc += Vs[i*32 + k] * fts[k];
            wv[i] = acc;
        } else {
            int e = tid - 128;                       // 0..383
            ((float4*)Qt)[e] = ((const float4*)Qsrc)[e];
            if (e < 192) ((float4*)Qt)[e + 384] = ((const float4*)Qsrc)[e + 384];
            if (e >= 192 && e < 204) ((float4*)qts)[e - 192] = ((const float4*)psrc)[e - 192];
        }
        __syncthreads();

        // ---- P1: Qt += F^T M ; qt += F^T w
        {
            int s = tid;
            if (s < 576) {
                int r = s / 12, cq = s % 12;
                float4 acc = ((float4*)Qt)[r*12 + cq];
                #pragma unroll
                for (int k = 0; k < 32; ++k) {
                    float f = Fs[k*48 + r];
                    float4 m4 = ((float4*)Ms)[k*12 + cq];
                    acc.x += f*m4.x; acc.y += f*m4.y; acc.z += f*m4.z; acc.w += f*m4.w;
                }
                ((float4*)Qt)[r*12 + cq] = acc;
            }
            s = tid + 512;
            if (s < 576) {
                int r = s / 12, cq = s % 12;
                float4 acc = ((float4*)Qt)[r*12 + cq];
                #pragma unroll
                for (int k = 0; k < 32; ++k) {
                    float f = Fs[k*48 + r];
                    float4 m4 = ((float4*)Ms)[k*12 + cq];
                    acc.x += f*m4.x; acc.y += f*m4.y; acc.z += f*m4.z; acc.w += f*m4.w;
                }
                ((float4*)Qt)[r*12 + cq] = acc;
            }
            if (tid >= 448 && tid < 496) {
                int c = tid - 448;
                float acc = qts[c];
                #pragma unroll
                for (int k = 0; k < 32; ++k) acc += Fs[k*48 + c] * wv[k];
                qts[c] = acc;
            }
        }
        __syncthreads();

        // ---- P2..P5: block-4 Jordan elimination on [Quu | Qux | qu] (16x49)
        // q=0: Qt/qts -> Wa ; q=1: Wa->Wb ; q=2: Wb->Wa ; q=3: Wa->Wb
        #pragma unroll
        for (int q = 0; q < 4; ++q) {
            const float* S = (q == 0) ? nullptr : ((q & 1) ? Wa : Wb);
            float*       D = (q & 1) ? Wb : Wa;
            const int pc = 32 + 4*q;

            float P[4][4], IP[4][4];
            #pragma unroll
            for (int m = 0; m < 4; ++m) {
                float4 row;
                if (q == 0) row = *((const float4*)(Qt + (32 + 4*q + m)*48 + pc));
                else        row = *((const float4*)(S + (4*q + m)*52 + pc));
                P[m][0]=row.x; P[m][1]=row.y; P[m][2]=row.z; P[m][3]=row.w;
            }
            inv4(P, IP);
            if (tid == 0) {
                #pragma unroll
                for (int e = 0; e < 16; ++e) invPs[q*16 + e] = IP[e>>2][e&3];
            }

            #pragma unroll
            for (int rep = 0; rep < 2; ++rep) {
                int e = tid + rep*512;
                if (e < 784) {
                    int r = e / 49, c = e % 49;
                    float val;
                    if (q == 0) {
                        float src_rc = (c < 48) ? Qt[(32+r)*48 + c] : qts[32 + r];
                        if ((r >> 2) == q) val = src_rc;
                        else {
                            float f0 = Qt[(32+r)*48 + pc + 0];
                            float f1 = Qt[(32+r)*48 + pc + 1];
                            float f2 = Qt[(32+r)*48 + pc + 2];
                            float f3 = Qt[(32+r)*48 + pc + 3];
                            float g0 = f0*IP[0][0]+f1*IP[1][0]+f2*IP[2][0]+f3*IP[3][0];
                            float g1 = f0*IP[0][1]+f1*IP[1][1]+f2*IP[2][1]+f3*IP[3][1];
                            float g2 = f0*IP[0][2]+f1*IP[1][2]+f2*IP[2][2]+f3*IP[3][2];
                            float g3 = f0*IP[0][3]+f1*IP[1][3]+f2*IP[2][3]+f3*IP[3][3];
                            float p0 = (c < 48) ? Qt[(32+0)*48 + c] : qts[32];
                            float p1 = (c < 48) ? Qt[(32+1)*48 + c] : qts[33];
                            float p2 = (c < 48) ? Qt[(32+2)*48 + c] : qts[34];
                            float p3 = (c < 48) ? Qt[(32+3)*48 + c] : qts[35];
                            val = src_rc - (g0*p0 + g1*p1 + g2*p2 + g3*p3);
                        }
                    } else {
                        float src_rc = S[r*52 + c];
                        if ((r >> 2) == q) val = src_rc;
                        else {
                            float f0 = S[r*52 + pc + 0];
                            float f1 = S[r*52 + pc + 1];
                            float f2 = S[r*52 + pc + 2];
                            float f3 = S[r*52 + pc + 3];
                            float g0 = f0*IP[0][0]+f1*IP[1][0]+f2*IP[2][0]+f3*IP[3][0];
                            float g1 = f0*IP[0][1]+f1*IP[1][1]+f2*IP[2][1]+f3*IP[3][1];
                            float g2 = f0*IP[0][2]+f1*IP[1][2]+f2*IP[2][2]+f3*IP[3][2];
                            float g3 = f0*IP[0][3]+f1*IP[1][3]+f2*IP[2][3]+f3*IP[3][3];
                            val = src_rc - (g0*S[(4*q+0)*52 + c] + g1*S[(4*q+1)*52 + c]
                                          + g2*S[(4*q+2)*52 + c] + g3*S[(4*q+3)*52 + c]);
                        }
                    }
                    D[r*52 + c] = val;
                }
            }
            __syncthreads();
        }

        // ---- P6: extract KK = Quu^{-1}[Qux | qu]; write -KK (=K,k) to global
        {
            float* base = Kws + (size_t)(b*TT + t) * 528;
            #pragma unroll
            for (int rep = 0; rep < 2; ++rep) {
                int e = tid + rep*512;
                if (e < 528) {
                    int rr = e / 33, cc = e % 33;
                    int c  = (cc < 32) ? cc : 48;
                    int q  = rr >> 2, m0 = (rr & 3) * 4;
                    float acc = invPs[q*16 + m0 + 0] * Wb[(4*q + 0)*52 + c]
                              + invPs[q*16 + m0 + 1] * Wb[(4*q + 1)*52 + c]
                              + invPs[q*16 + m0 + 2] * Wb[(4*q + 2)*52 + c]
                              + invPs[q*16 + m0 + 3] * Wb[(4*q + 3)*52 + c];
                    KK[rr*52 + c] = acc;
                    if (cc < 32) base[cc*16 + rr] = -acc;   // KT[j][i]
                    else         base[512 + rr]  = -acc;    // k[i]
                }
            }
        }
        __syncthreads();

        // ---- P7a: Vtmp = Qxx - Qxu*KK  (into Ms); v' = qx - Qxu*kk
        if (tid < 256) {
            int i = tid >> 3, jq = tid & 7;
            float qx[16];
            #pragma unroll
            for (int kq = 0; kq < 4; ++kq) {
                float4 v4 = *((const float4*)(Qt + i*48 + 32 + kq*4));
                qx[kq*4+0]=v4.x; qx[kq*4+1]=v4.y; qx[kq*4+2]=v4.z; qx[kq*4+3]=v4.w;
            }
            float4 acc = ((float4*)Qt)[i*12 + jq];
            #pragma unroll
            for (int k = 0; k < 16; ++k) {
                float4 kk4 = *((const float4*)(KK + k*52 + jq*4));
                acc.x -= qx[k]*kk4.x; acc.y -= qx[k]*kk4.y;
                acc.z -= qx[k]*kk4.z; acc.w -= qx[k]*kk4.w;
            }
            ((float4*)Ms)[i*12 + jq] = acc;
        } else if (tid < 288) {
            int i = tid - 256;
            float acc = qts[i];
            #pragma unroll
            for (int k = 0; k < 16; ++k) acc -= Qt[i*48 + 32 + k] * KK[k*52 + 48];
            vsv[i] = acc;
        }
        __syncthreads();

        // ---- P7b: V = 0.5*(Vtmp + Vtmp^T)  (exactly symmetric)
        #pragma unroll
        for (int rep = 0; rep < 2; ++rep) {
            int e = tid + rep*512;
            int i = e >> 5, j = e & 31;
            if (i <= j) {
                float sv = 0.5f * (Ms[i*48 + j] + Ms[j*48 + i]);
                Vs[i*32 + j] = sv; Vs[j*32 + i] = sv;
            }
        }
        __syncthreads();
    }
}

// ---------------------------------------------------------------------------
// Kernel B: forward rollout, one wave per batch. Writes xs, us, taus.
// ---------------------------------------------------------------------------
__global__ __launch_bounds__(64, 1)
void lqr_forward(const float* __restrict__ Kws, const float* __restrict__ A,
                 const float* __restrict__ Bm, const float* __restrict__ c1,
                 const float* __restrict__ x_init,
                 float* __restrict__ xs, float* __restrict__ us,
                 float* __restrict__ taus)
{
    const int b = blockIdx.x, l = threadIdx.x;
    __shared__ __align__(16) float Fb[32*48];
    __shared__ __align__(16) float Kb[544];
    __shared__ float c1s[32], xu[48];

    for (int s = l; s < 256; s += 64) {
        int k = s >> 3, q = s & 7;
        ((float4*)Fb)[k*12 + q] = ((const float4*)A)[(b*32 + k)*8 + q];
    }
    for (int s = l; s < 128; s += 64) {
        int k = s >> 2, q = s & 3;
        ((float4*)Fb)[k*12 + 8 + q] = ((const float4*)Bm)[(b*32 + k)*4 + q];
    }
    if (l < 32) { c1s[l] = c1[b*32 + l]; xu[l] = x_init[b*32 + l]; }
    __syncthreads();

    for (int t = 0; t < TT; ++t) {
        const float4* src = (const float4*)(Kws + (size_t)(b*TT + t) * 528);
        ((float4*)Kb)[l]      = src[l];
        ((float4*)Kb)[l + 64] = src[l + 64];
        if (l < 4) ((float4*)Kb)[l + 128] = src[l + 128];
        __syncthreads();

        // u = K x + k   (KT stored as [j][i], j<32 state, i<16 ctrl)
        float part = 0.0f;
        int i = l & 15, g = l >> 4;
        #pragma unroll
        for (int jj = 0; jj < 8; ++jj) {
            int j = g*8 + jj;
            part += Kb[j*16 + i] * xu[j];
        }
        part += __shfl_down(part, 32);
        part += __shfl_down(part, 16);
        float ui = part + Kb[512 + i];
        if (l < 16) {
            xu[32 + l] = ui;
            us[(size_t)(t*64 + b)*16 + l] = ui;
        }
        __syncthreads();

        if (l < 32) xs[(size_t)(t*64 + b)*32 + l] = xu[l];
        if (l < 48) taus[(size_t)(t*64 + b)*48 + l] = xu[l];

        // xn = F xu + c1
        float pn = 0.0f;
        int i2 = l & 31, h = l >> 5;
        #pragma unroll
        for (int jj = 0; jj < 24; ++jj) {
            int j = h*24 + jj;
            pn += Fb[i2*48 + j] * xu[j];
        }
        pn += __shfl_down(pn, 32);
        float xni = pn + ((l < 32) ? c1s[i2] : 0.0f);
        __syncthreads();
        if (l < 32) xu[l] = xni;
        __syncthreads();
    }
}

// ---------------------------------------------------------------------------
// Kernel C: objs[t,b] = 0.5*xu^T Q xu + xu.p   (fully parallel, mem-bound)
// ---------------------------------------------------------------------------
__global__ __launch_bounds__(256, 4)
void lqr_obj(const float* __restrict__ Q, const float* __restrict__ p,
             const float* __restrict__ taus, float* __restrict__ objs)
{
    const int bi = blockIdx.x;            // = b*T + t
    const int b = bi >> 7, t = bi & 127;
    const int tid = threadIdx.x;
    __shared__ float xu[48];
    __shared__ float red[8];
    const float* tp = taus + (size_t)(t*64 + b)*48;
    if (tid < 48) xu[tid] = tp[tid];
    __syncthreads();

    const float4* Q4 = (const float4*)(Q + (size_t)bi * 2304);
    float acc = 0.0f;
    for (int e4 = tid; e4 < 576; e4 += 256) {
        float4 qv = Q4[e4];
        int r = e4 / 12, c = (e4 % 12) * 4;
        float xr = xu[r];
        acc += xr * (qv.x*xu[c] + qv.y*xu[c+1] + qv.z*xu[c+2] + qv.w*xu[c+3]);
    }
    acc *= 0.5f;
    if (tid < 48) acc += xu[tid] * p[(size_t)bi*48 + tid];

    #pragma unroll
    for (int off = 32; off > 0; off >>= 1) acc += __shfl_down(acc, off);
    if ((tid & 63) == 0) red[tid >> 6] = acc;
    __syncthreads();
    if (tid == 0) objs[(t << 6) + b] = red[0] + red[1] + red[2] + red[3];
}

// ---------------------------------------------------------------------------
extern "C" void kernel_launch(void* const* d_in, const int* in_sizes, int n_in,
                              void* d_out, int out_size, void* d_ws, size_t ws_size,
                              hipStream_t stream) {
    const float* x_init = (const float*)d_in[0];
    const float* Q      = (const float*)d_in[1];
    const float* p      = (const float*)d_in[2];
    const float* A      = (const float*)d_in[3];
    const float* Bm     = (const float*)d_in[4];
    const float* c1     = (const float*)d_in[5];

    float* out  = (float*)d_out;
    float* xs   = out;                       // 128*64*32 = 262144
    float* us   = out + 262144;              // 128*64*16 = 131072
    float* objs = out + 393216;              // 128*64    = 8192
    float* taus = out + 401408;              // 128*64*48 = 393216

    float* Kws = (float*)d_ws;               // 64*128*528 floats = 17.3 MB

    lqr_backward<<<NBATCH, 512, 0, stream>>>(Q, p, A, Bm, c1, Kws);
    lqr_forward<<<NBATCH, 64, 0, stream>>>(Kws, A, Bm, c1, x_init, xs, us, taus);
    lqr_obj<<<NBATCH*TT, 256, 0, stream>>>(Q, p, taus, objs);
}

// Round 3
// 838.194 us; speedup vs baseline: 1.0788x; 1.0788x over previous
//
#include <hip/hip_runtime.h>

#define TT     128
#define NBATCH 64

// raw barrier: drain this wave's LDS ops, then barrier. Single asm with
// memory clobber so no memory op can cross it. Deliberately NO vmcnt drain
// (keeps the async Qt prefetch in flight across phases).
#define BAR()  asm volatile("s_waitcnt lgkmcnt(0)\n\ts_barrier" ::: "memory")
#define BARV() asm volatile("s_waitcnt vmcnt(0) lgkmcnt(0)\n\ts_barrier" ::: "memory")

__device__ __forceinline__ void gload16(const float* g, float* l) {
    __builtin_amdgcn_global_load_lds(
        (__attribute__((address_space(1))) void*)g,
        (__attribute__((address_space(3))) void*)l, 16, 0, 0);
}

// closed-form 4x4 inverse via 2x2 blocks (SPD pivot blocks, no pivoting)
__device__ __forceinline__ void inv4(const float4 pr[4], float IP[4][4]) {
    float a00=pr[0].x, a01=pr[0].y, a10=pr[1].x, a11=pr[1].y;
    float b00=pr[0].z, b01=pr[0].w, b10=pr[1].z, b11=pr[1].w;
    float c00=pr[2].x, c01=pr[2].y, c10=pr[3].x, c11=pr[3].y;
    float d00=pr[2].z, d01=pr[2].w, d10=pr[3].z, d11=pr[3].w;
    float r = 1.0f / (a00*a11 - a01*a10);
    float ia00 =  a11*r, ia01 = -a01*r, ia10 = -a10*r, ia11 = a00*r;
    float t00 = ia00*b00 + ia01*b10, t01 = ia00*b01 + ia01*b11;
    float t10 = ia10*b00 + ia11*b10, t11 = ia10*b01 + ia11*b11;
    float u00 = c00*ia00 + c01*ia10, u01 = c00*ia01 + c01*ia11;
    float u10 = c10*ia00 + c11*ia10, u11 = c10*ia01 + c11*ia11;
    float s00 = d00 - (c00*t00 + c01*t10), s01 = d01 - (c00*t01 + c01*t11);
    float s10 = d10 - (c10*t00 + c11*t10), s11 = d11 - (c10*t01 + c11*t11);
    float rs = 1.0f / (s00*s11 - s01*s10);
    float is00 =  s11*rs, is01 = -s01*rs, is10 = -s10*rs, is11 = s00*rs;
    float su00 = is00*u00 + is01*u10, su01 = is00*u01 + is01*u11;
    float su10 = is10*u00 + is11*u10, su11 = is10*u01 + is11*u11;
    IP[0][0] = ia00 + (t00*su00 + t01*su10);
    IP[0][1] = ia01 + (t00*su01 + t01*su11);
    IP[1][0] = ia10 + (t10*su00 + t11*su10);
    IP[1][1] = ia11 + (t10*su01 + t11*su11);
    IP[0][2] = -(t00*is00 + t01*is10);  IP[0][3] = -(t00*is01 + t01*is11);
    IP[1][2] = -(t10*is00 + t11*is10);  IP[1][3] = -(t10*is01 + t11*is11);
    IP[2][0] = -su00; IP[2][1] = -su01;
    IP[3][0] = -su10; IP[3][1] = -su11;
    IP[2][2] = is00;  IP[2][3] = is01;
    IP[3][2] = is10;  IP[3][3] = is11;
}

// ---------------------------------------------------------------------------
// Backward Riccati. One block (256 thr) per batch. 8 raw barriers/step,
// double-buffered Qt prefetch via global_load_lds.
// Augmented system layout: [Qux (cols 0..31) | Quu (cols 32..47) | qu (48)].
// After full block-GJ, cols 0..31 = Quu^-1 Qux = KK, col 48 = Quu^-1 qu = kk.
// Writes KT[32][16] + k[16] (528 floats) per (b,t).
// ---------------------------------------------------------------------------
__global__ __launch_bounds__(256, 1)
void lqr_backward(const float* __restrict__ Q, const float* __restrict__ p,
                  const float* __restrict__ A, const float* __restrict__ Bm,
                  const float* __restrict__ c1, float* __restrict__ Kws)
{
    const int b   = blockIdx.x;
    const int tid = threadIdx.x;

    __shared__ __align__(16) float Fs[32*52];    // F rows, stride 52
    __shared__ __align__(16) float FTs[48*33];   // F^T, stride 33
    __shared__ __align__(16) float Vs[32*36];    // V, stride 36
    __shared__ __align__(16) float Ms[32*52];    // M = V F / scratch, stride 52
    __shared__ __align__(16) float Qtb[2][48*48];// Qt double buffer (linear!)
    __shared__ __align__(16) float qtb[2][256];  // qt double buffer (padded)
    __shared__ __align__(16) float Wa[16*52];
    __shared__ __align__(16) float Wb[16*52];
    __shared__ float vsv[32], fts[32], wv[32];

    // ---- init: F, F^T, V=0, v=0, ft
    for (int s = tid; s < 256; s += 256) {
        int k = s >> 3, q = s & 7;
        float4 v = ((const float4*)A)[(b*32 + k)*8 + q];
        ((float4*)(Fs + k*52))[q] = v;
        FTs[(4*q+0)*33 + k] = v.x; FTs[(4*q+1)*33 + k] = v.y;
        FTs[(4*q+2)*33 + k] = v.z; FTs[(4*q+3)*33 + k] = v.w;
    }
    for (int s = tid; s < 128; s += 256) {
        int k = s >> 2, q = s & 3;
        float4 v = ((const float4*)Bm)[(b*32 + k)*4 + q];
        ((float4*)(Fs + k*52))[8 + q] = v;
        FTs[(32+4*q+0)*33 + k] = v.x; FTs[(32+4*q+1)*33 + k] = v.y;
        FTs[(32+4*q+2)*33 + k] = v.z; FTs[(32+4*q+3)*33 + k] = v.w;
    }
    for (int s = tid; s < 288; s += 256) ((float4*)Vs)[s] = make_float4(0,0,0,0);
    if (tid < 32) { vsv[tid] = 0.0f; fts[tid] = c1[b*32 + tid]; }

    // ---- stage Qt[127], p[127] into buffer 0
    {
        const float* Qs0 = Q + (size_t)(b*TT + TT-1) * 2304;
        #pragma unroll
        for (int r = 0; r < 3; ++r) {
            int e = r*256 + tid;
            if (e < 576) gload16(Qs0 + e*4, Qtb[0] + e*4);
        }
        if (tid < 12) gload16(p + (size_t)(b*TT + TT-1)*48 + tid*4, qtb[0] + tid*4);
    }
    BARV();

    for (int t = TT-1; t >= 0; --t) {
        const int cur = (TT-1 - t) & 1;
        float* Qtc = Qtb[cur];
        float* qtc = qtb[cur];

        // ================= Phase A: M = V*F (2x4 tiles, 192 thr) ||
        //                   prefetch Qt[t-1] + w = V ft + v (wave 3)
        if (tid < 192) {
            const int i0 = (tid/12)*2, jq = tid%12;
            float4 a0 = make_float4(0,0,0,0), a1 = make_float4(0,0,0,0);
            #pragma unroll
            for (int k = 0; k < 32; ++k) {
                float v0 = Vs[k*36 + i0], v1 = Vs[k*36 + i0 + 1];
                float4 f = ((const float4*)(Fs + k*52))[jq];
                a0.x += v0*f.x; a0.y += v0*f.y; a0.z += v0*f.z; a0.w += v0*f.w;
                a1.x += v1*f.x; a1.y += v1*f.y; a1.z += v1*f.z; a1.w += v1*f.w;
            }
            ((float4*)(Ms + (i0  )*52))[jq] = a0;
            ((float4*)(Ms + (i0+1)*52))[jq] = a1;
        } else {
            const int idx = tid - 192;
            if (t > 0) {
                const float* Qs = Q + (size_t)(b*TT + t-1) * 2304;
                float* dst = Qtb[cur ^ 1];
                #pragma unroll
                for (int r = 0; r < 9; ++r) {
                    int e = r*64 + idx;
                    gload16(Qs + e*4, dst + e*4);
                }
                if (idx < 12) gload16(p + (size_t)(b*TT + t-1)*48 + idx*4,
                                      qtb[cur ^ 1] + idx*4);
            }
            if (idx < 32) {
                float acc = vsv[idx];
                #pragma unroll
                for (int k = 0; k < 32; ++k) acc += Vs[idx*36 + k] * fts[k];
                wv[idx] = acc;
            }
        }
        BAR();

        // ================= Phase B: Qt += F^T M (3x4 tiles, 192 thr) ||
        //                   qt += F^T w (48 thr)
        if (tid < 192) {
            const int r0 = (tid/12)*3, cq = tid%12;
            float4 a0 = ((float4*)Qtc)[(r0+0)*12 + cq];
            float4 a1 = ((float4*)Qtc)[(r0+1)*12 + cq];
            float4 a2 = ((float4*)Qtc)[(r0+2)*12 + cq];
            #pragma unroll
            for (int k = 0; k < 32; ++k) {
                float f0 = FTs[(r0+0)*33 + k];
                float f1 = FTs[(r0+1)*33 + k];
                float f2 = FTs[(r0+2)*33 + k];
                float4 m4 = ((const float4*)Ms)[k*13 + cq];
                a0.x += f0*m4.x; a0.y += f0*m4.y; a0.z += f0*m4.z; a0.w += f0*m4.w;
                a1.x += f1*m4.x; a1.y += f1*m4.y; a1.z += f1*m4.z; a1.w += f1*m4.w;
                a2.x += f2*m4.x; a2.y += f2*m4.y; a2.z += f2*m4.z; a2.w += f2*m4.w;
            }
            ((float4*)Qtc)[(r0+0)*12 + cq] = a0;
            ((float4*)Qtc)[(r0+1)*12 + cq] = a1;
            ((float4*)Qtc)[(r0+2)*12 + cq] = a2;
        } else if (tid < 240) {
            const int c = tid - 192;
            float acc = qtc[c];
            #pragma unroll
            for (int k = 0; k < 32; ++k) acc += FTs[c*33 + k] * wv[k];
            qtc[c] = acc;
        }
        BAR();

        // ================= Jordan q=0..3: full block Gauss-Jordan on
        // [Qux | Quu | qu] (16x49). Pivot cols are 32+4q..32+4q+3.
        // After q=3: cols 0..31 = KK, col 48 = kk (K = -KK, k = -kk).
        float* Kbase = Kws + (size_t)(b*TT + t) * 528;
        #pragma unroll
        for (int q = 0; q < 4; ++q) {
            const float* S = (q == 0) ? nullptr : ((q & 1) ? Wa : Wb);
            float*       D = (q & 1) ? Wb : Wa;
            const int pc = 4*q;           // pivot col within Quu block

            // pivot block rows (broadcast reads), invert redundantly
            float4 pr[4];
            #pragma unroll
            for (int m = 0; m < 4; ++m) {
                if (q == 0) pr[m] = *(const float4*)(Qtc + (32 + m)*48 + 32);
                else        pr[m] = *(const float4*)(S + (4*q + m)*52 + 32 + pc);
            }
            float IP[4][4];
            inv4(pr, IP);

            if (tid < 196) {
                const int c  = tid >> 2;      // 0..48
                const int rg = tid & 3;       // row group
                float sn[4], R[4];
                #pragma unroll
                for (int n = 0; n < 4; ++n) {
                    int rr = 4*q + n;
                    sn[n] = (q == 0) ? ((c < 48) ? Qtc[(32+rr)*48 + c] : qtc[32 + rr])
                                     : S[rr*52 + c];
                }
                #pragma unroll
                for (int m = 0; m < 4; ++m)
                    R[m] = IP[m][0]*sn[0] + IP[m][1]*sn[1] + IP[m][2]*sn[2] + IP[m][3]*sn[3];

                #pragma unroll
                for (int i2 = 0; i2 < 4; ++i2) {
                    const int r = 4*rg + i2;
                    float val;
                    if (rg == q) {
                        val = R[i2];
                    } else {
                        float4 f;
                        if (q == 0) f = *(const float4*)(Qtc + (32 + r)*48 + 32);
                        else        f = *(const float4*)(S + r*52 + 32 + pc);
                        float src = (q == 0) ? ((c < 48) ? Qtc[(32+r)*48 + c] : qtc[32 + r])
                                             : S[r*52 + c];
                        val = src - (f.x*R[0] + f.y*R[1] + f.z*R[2] + f.w*R[3]);
                    }
                    D[r*52 + c] = val;
                    if (q == 3) {
                        if (c < 32)       Kbase[c*16 + r] = -val;  // KT[state][ctrl]
                        else if (c == 48) Kbase[512 + r]  = -val;  // k[ctrl]
                    }
                }
            }
            BAR();
        }

        // ================= P7a: Vtmp = Qxx - Qxu*KK  (256 thr, row x float4)
        // KK = Wb cols 0..31.
        {
            const int i = tid >> 3, jq = tid & 7;
            float4 acc = ((float4*)Qtc)[i*12 + jq];
            float qx[16];
            #pragma unroll
            for (int kq = 0; kq < 4; ++kq) {
                float4 v4 = ((float4*)Qtc)[i*12 + 8 + kq];
                qx[kq*4+0] = v4.x; qx[kq*4+1] = v4.y;
                qx[kq*4+2] = v4.z; qx[kq*4+3] = v4.w;
            }
            #pragma unroll
            for (int k = 0; k < 16; ++k) {
                float4 kk = ((const float4*)Wb)[k*13 + jq];
                acc.x -= qx[k]*kk.x; acc.y -= qx[k]*kk.y;
                acc.z -= qx[k]*kk.z; acc.w -= qx[k]*kk.w;
            }
            ((float4*)Ms)[i*13 + jq] = acc;
        }
        BAR();

        // ================= P7b: v' = qx - Qxu*kk ; V = 0.5*(W + W^T)
        if (tid < 32) {
            float acc = qtc[tid];
            #pragma unroll
            for (int k = 0; k < 16; ++k)
                acc -= Qtc[tid*48 + 32 + k] * Wb[k*52 + 48];
            vsv[tid] = acc;
        }
        #pragma unroll
        for (int rep = 0; rep < 4; ++rep) {
            int e = tid + rep*256;
            int i = e >> 5, j = e & 31;
            if (i <= j) {
                float sv = 0.5f * (Ms[i*52 + j] + Ms[j*52 + i]);
                Vs[i*36 + j] = sv; Vs[j*36 + i] = sv;
            }
        }
        BARV();   // also drains this step's prefetch loads + K stores
    }
}

// ---------------------------------------------------------------------------
// Forward rollout, one wave per batch. Writes xs, us, taus.
// ---------------------------------------------------------------------------
__global__ __launch_bounds__(64, 1)
void lqr_forward(const float* __restrict__ Kws, const float* __restrict__ A,
                 const float* __restrict__ Bm, const float* __restrict__ c1,
                 const float* __restrict__ x_init,
                 float* __restrict__ xs, float* __restrict__ us,
                 float* __restrict__ taus)
{
    const int b = blockIdx.x, l = threadIdx.x;
    __shared__ __align__(16) float Fb[32*48];
    __shared__ __align__(16) float Kb[544];
    __shared__ float c1s[32], xu[48];

    for (int s = l; s < 256; s += 64) {
        int k = s >> 3, q = s & 7;
        ((float4*)Fb)[k*12 + q] = ((const float4*)A)[(b*32 + k)*8 + q];
    }
    for (int s = l; s < 128; s += 64) {
        int k = s >> 2, q = s & 3;
        ((float4*)Fb)[k*12 + 8 + q] = ((const float4*)Bm)[(b*32 + k)*4 + q];
    }
    if (l < 32) { c1s[l] = c1[b*32 + l]; xu[l] = x_init[b*32 + l]; }
    __syncthreads();

    for (int t = 0; t < TT; ++t) {
        const float4* src = (const float4*)(Kws + (size_t)(b*TT + t) * 528);
        ((float4*)Kb)[l]      = src[l];
        ((float4*)Kb)[l + 64] = src[l + 64];
        if (l < 4) ((float4*)Kb)[l + 128] = src[l + 128];
        __syncthreads();

        // u = K x + k   (KT stored as [j][i])
        float part = 0.0f;
        int i = l & 15, g = l >> 4;
        #pragma unroll
        for (int jj = 0; jj < 8; ++jj) {
            int j = g*8 + jj;
            part += Kb[j*16 + i] * xu[j];
        }
        part += __shfl_down(part, 32);
        part += __shfl_down(part, 16);
        float ui = part + Kb[512 + i];
        if (l < 16) {
            xu[32 + l] = ui;
            us[(size_t)(t*64 + b)*16 + l] = ui;
        }
        __syncthreads();

        if (l < 32) xs[(size_t)(t*64 + b)*32 + l] = xu[l];
        if (l < 48) taus[(size_t)(t*64 + b)*48 + l] = xu[l];

        // xn = F xu + c1
        float pn = 0.0f;
        int i2 = l & 31, h = l >> 5;
        #pragma unroll
        for (int jj = 0; jj < 24; ++jj) {
            int j = h*24 + jj;
            pn += Fb[i2*48 + j] * xu[j];
        }
        pn += __shfl_down(pn, 32);
        float xni = pn + ((l < 32) ? c1s[i2] : 0.0f);
        __syncthreads();
        if (l < 32) xu[l] = xni;
        __syncthreads();
    }
}

// ---------------------------------------------------------------------------
// objs[t,b] = 0.5*xu^T Q xu + xu.p   (fully parallel, mem-bound)
// ---------------------------------------------------------------------------
__global__ __launch_bounds__(256, 4)
void lqr_obj(const float* __restrict__ Q, const float* __restrict__ p,
             const float* __restrict__ taus, float* __restrict__ objs)
{
    const int bi = blockIdx.x;            // = b*T + t
    const int b = bi >> 7, t = bi & 127;
    const int tid = threadIdx.x;
    __shared__ float xu[48];
    __shared__ float red[8];
    const float* tp = taus + (size_t)(t*64 + b)*48;
    if (tid < 48) xu[tid] = tp[tid];
    __syncthreads();

    const float4* Q4 = (const float4*)(Q + (size_t)bi * 2304);
    float acc = 0.0f;
    for (int e4 = tid; e4 < 576; e4 += 256) {
        float4 qv = Q4[e4];
        int r = e4 / 12, c = (e4 % 12) * 4;
        float xr = xu[r];
        acc += xr * (qv.x*xu[c] + qv.y*xu[c+1] + qv.z*xu[c+2] + qv.w*xu[c+3]);
    }
    acc *= 0.5f;
    if (tid < 48) acc += xu[tid] * p[(size_t)bi*48 + tid];

    #pragma unroll
    for (int off = 32; off > 0; off >>= 1) acc += __shfl_down(acc, off);
    if ((tid & 63) == 0) red[tid >> 6] = acc;
    __syncthreads();
    if (tid == 0) objs[(t << 6) + b] = red[0] + red[1] + red[2] + red[3];
}

// ---------------------------------------------------------------------------
extern "C" void kernel_launch(void* const* d_in, const int* in_sizes, int n_in,
                              void* d_out, int out_size, void* d_ws, size_t ws_size,
                              hipStream_t stream) {
    const float* x_init = (const float*)d_in[0];
    const float* Q      = (const float*)d_in[1];
    const float* p      = (const float*)d_in[2];
    const float* A      = (const float*)d_in[3];
    const float* Bm     = (const float*)d_in[4];
    const float* c1     = (const float*)d_in[5];

    float* out  = (float*)d_out;
    float* xs   = out;                       // 128*64*32 = 262144
    float* us   = out + 262144;              // 128*64*16 = 131072
    float* objs = out + 393216;              // 128*64    = 8192
    float* taus = out + 401408;              // 128*64*48 = 393216

    float* Kws = (float*)d_ws;               // 64*128*528 floats = 17.3 MB

    lqr_backward<<<NBATCH, 256, 0, stream>>>(Q, p, A, Bm, c1, Kws);
    lqr_forward<<<NBATCH, 64, 0, stream>>>(Kws, A, Bm, c1, x_init, xs, us, taus);
    lqr_obj<<<NBATCH*TT, 256, 0, stream>>>(Q, p, taus, objs);
}

// Round 4
// 780.576 us; speedup vs baseline: 1.1584x; 1.0738x over previous
//
#include <hip/hip_runtime.h>

#define TT     128
#define NBATCH 64

// raw barrier: drain this wave's LDS ops, then barrier. No vmcnt drain --
// keeps async Qt prefetch in flight across phases.
#define BAR()  asm volatile("s_waitcnt lgkmcnt(0)\n\ts_barrier" ::: "memory")
#define BARV() asm volatile("s_waitcnt vmcnt(0) lgkmcnt(0)\n\ts_barrier" ::: "memory")

__device__ __forceinline__ void gload16(const float* g, float* l) {
    __builtin_amdgcn_global_load_lds(
        (__attribute__((address_space(1))) void*)g,
        (__attribute__((address_space(3))) void*)l, 16, 0, 0);
}

// closed-form 4x4 inverse via 2x2 blocks (SPD pivot blocks, no pivoting)
__device__ __forceinline__ void inv4(const float4 pr[4], float IP[4][4]) {
    float a00=pr[0].x, a01=pr[0].y, a10=pr[1].x, a11=pr[1].y;
    float b00=pr[0].z, b01=pr[0].w, b10=pr[1].z, b11=pr[1].w;
    float c00=pr[2].x, c01=pr[2].y, c10=pr[3].x, c11=pr[3].y;
    float d00=pr[2].z, d01=pr[2].w, d10=pr[3].z, d11=pr[3].w;
    float r = 1.0f / (a00*a11 - a01*a10);
    float ia00 =  a11*r, ia01 = -a01*r, ia10 = -a10*r, ia11 = a00*r;
    float t00 = ia00*b00 + ia01*b10, t01 = ia00*b01 + ia01*b11;
    float t10 = ia10*b00 + ia11*b10, t11 = ia10*b01 + ia11*b11;
    float u00 = c00*ia00 + c01*ia10, u01 = c00*ia01 + c01*ia11;
    float u10 = c10*ia00 + c11*ia10, u11 = c10*ia01 + c11*ia11;
    float s00 = d00 - (c00*t00 + c01*t10), s01 = d01 - (c00*t01 + c01*t11);
    float s10 = d10 - (c10*t00 + c11*t10), s11 = d11 - (c10*t01 + c11*t11);
    float rs = 1.0f / (s00*s11 - s01*s10);
    float is00 =  s11*rs, is01 = -s01*rs, is10 = -s10*rs, is11 = s00*rs;
    float su00 = is00*u00 + is01*u10, su01 = is00*u01 + is01*u11;
    float su10 = is10*u00 + is11*u10, su11 = is10*u01 + is11*u11;
    IP[0][0] = ia00 + (t00*su00 + t01*su10);
    IP[0][1] = ia01 + (t00*su01 + t01*su11);
    IP[1][0] = ia10 + (t10*su00 + t11*su10);
    IP[1][1] = ia11 + (t10*su01 + t11*su11);
    IP[0][2] = -(t00*is00 + t01*is10);  IP[0][3] = -(t00*is01 + t01*is11);
    IP[1][2] = -(t10*is00 + t11*is10);  IP[1][3] = -(t10*is01 + t11*is11);
    IP[2][0] = -su00; IP[2][1] = -su01;
    IP[3][0] = -su10; IP[3][1] = -su11;
    IP[2][2] = is00;  IP[2][3] = is01;
    IP[3][2] = is10;  IP[3][3] = is11;
}

// ---------------------------------------------------------------------------
// Backward Riccati. One block (256 thr) per batch. 7 raw barriers/step.
// Phases: A (M=V*F) | B (Xs = Qt + F^T M, padded stride 52) |
//         G0..G3 (block GJ on [Qux|Quu|qu], uniform stride-52 path) |
//         P7 (V' = Qxx' - Qxu'*KK direct, v').
// Writes KT[32][16] + k[16] (528 floats) per (b,t).
// ---------------------------------------------------------------------------
__global__ __launch_bounds__(256, 1)
void lqr_backward(const float* __restrict__ Q, const float* __restrict__ p,
                  const float* __restrict__ A, const float* __restrict__ Bm,
                  const float* __restrict__ c1, float* __restrict__ Kws)
{
    const int b   = blockIdx.x;
    const int tid = threadIdx.x;

    __shared__ __align__(16) float Fs[32*52];    // F rows, stride 52
    __shared__ __align__(16) float Vs[32*36];    // V, stride 36
    __shared__ __align__(16) float Ms[32*52];    // M = V F, stride 52
    __shared__ __align__(16) float Xs[48*52];    // Qt_new, stride 52 (col48=qu)
    __shared__ __align__(16) float Qtb[2][48*48];// staged Qt double buffer
    __shared__ __align__(16) float qtb[2][256];  // staged p double buffer
    __shared__ __align__(16) float Wa[16*52];
    __shared__ __align__(16) float Wb[16*52];
    __shared__ float vsv[32], fts[32], wv[32];

    // ---- init: F (row-major only), V=0, v=0, ft
    for (int s = tid; s < 256; s += 256) {
        int k = s >> 3, q = s & 7;
        ((float4*)(Fs + k*52))[q] = ((const float4*)A)[(b*32 + k)*8 + q];
    }
    for (int s = tid; s < 128; s += 256) {
        int k = s >> 2, q = s & 3;
        ((float4*)(Fs + k*52))[8 + q] = ((const float4*)Bm)[(b*32 + k)*4 + q];
    }
    for (int s = tid; s < 288; s += 256) ((float4*)Vs)[s] = make_float4(0,0,0,0);
    if (tid < 32) { vsv[tid] = 0.0f; fts[tid] = c1[b*32 + tid]; }

    // ---- stage Qt[127], p[127] into buffer 0
    {
        const float* Qs0 = Q + (size_t)(b*TT + TT-1) * 2304;
        #pragma unroll
        for (int r = 0; r < 3; ++r) {
            int e = r*256 + tid;
            if (e < 576) gload16(Qs0 + e*4, Qtb[0] + e*4);
        }
        if (tid < 12) gload16(p + (size_t)(b*TT + TT-1)*48 + tid*4, qtb[0] + tid*4);
    }
    BARV();

    for (int t = TT-1; t >= 0; --t) {
        const int cur = (TT-1 - t) & 1;
        float* Qtc = Qtb[cur];
        float* qtc = qtb[cur];

        // ========== Phase A: M = V*F (4x4 tiles, 96 thr) ||
        //            wave 3: prefetch Qt[t-1] + w = V ft + v
        if (tid < 96) {
            const int i0 = (tid/12)*4, c0 = (tid%12)*4;
            float4 a0 = make_float4(0,0,0,0), a1 = a0, a2 = a0, a3 = a0;
            #pragma unroll
            for (int k = 0; k < 32; ++k) {
                float4 v = *(const float4*)(Vs + k*36 + i0);   // V[k][i0..3]
                float4 f = *(const float4*)(Fs + k*52 + c0);   // F[k][c0..3]
                a0.x += v.x*f.x; a0.y += v.x*f.y; a0.z += v.x*f.z; a0.w += v.x*f.w;
                a1.x += v.y*f.x; a1.y += v.y*f.y; a1.z += v.y*f.z; a1.w += v.y*f.w;
                a2.x += v.z*f.x; a2.y += v.z*f.y; a2.z += v.z*f.z; a2.w += v.z*f.w;
                a3.x += v.w*f.x; a3.y += v.w*f.y; a3.z += v.w*f.z; a3.w += v.w*f.w;
            }
            *(float4*)(Ms + (i0+0)*52 + c0) = a0;
            *(float4*)(Ms + (i0+1)*52 + c0) = a1;
            *(float4*)(Ms + (i0+2)*52 + c0) = a2;
            *(float4*)(Ms + (i0+3)*52 + c0) = a3;
        } else if (tid >= 192) {
            const int idx = tid - 192;
            if (t > 0) {
                const float* Qs = Q + (size_t)(b*TT + t-1) * 2304;
                float* dst = Qtb[cur ^ 1];
                #pragma unroll
                for (int r = 0; r < 9; ++r) {
                    int e = r*64 + idx;
                    gload16(Qs + e*4, dst + e*4);
                }
                if (idx < 12) gload16(p + (size_t)(b*TT + t-1)*48 + idx*4,
                                      qtb[cur ^ 1] + idx*4);
            }
            if (idx < 32) {
                float acc = vsv[idx];
                #pragma unroll
                for (int k = 0; k < 32; ++k) acc += Vs[idx*36 + k] * fts[k];
                wv[idx] = acc;
            }
        }
        BAR();

        // ========== Phase B: Xs = Qt + F^T M  (4x4 tiles, 144 thr) ||
        //            qt crew (48 thr): qtc += F^T w, mirror qu into Xs col 48
        if (tid < 144) {
            const int r0 = (tid/12)*4, c0 = (tid%12)*4;
            float4 a0 = *(const float4*)(Qtc + (r0+0)*48 + c0);
            float4 a1 = *(const float4*)(Qtc + (r0+1)*48 + c0);
            float4 a2 = *(const float4*)(Qtc + (r0+2)*48 + c0);
            float4 a3 = *(const float4*)(Qtc + (r0+3)*48 + c0);
            #pragma unroll
            for (int k = 0; k < 32; ++k) {
                float4 fr = *(const float4*)(Fs + k*52 + r0);  // F[k][r0..3]
                float4 mc = *(const float4*)(Ms + k*52 + c0);  // M[k][c0..3]
                a0.x += fr.x*mc.x; a0.y += fr.x*mc.y; a0.z += fr.x*mc.z; a0.w += fr.x*mc.w;
                a1.x += fr.y*mc.x; a1.y += fr.y*mc.y; a1.z += fr.y*mc.z; a1.w += fr.y*mc.w;
                a2.x += fr.z*mc.x; a2.y += fr.z*mc.y; a2.z += fr.z*mc.z; a2.w += fr.z*mc.w;
                a3.x += fr.w*mc.x; a3.y += fr.w*mc.y; a3.z += fr.w*mc.z; a3.w += fr.w*mc.w;
            }
            *(float4*)(Xs + (r0+0)*52 + c0) = a0;
            *(float4*)(Xs + (r0+1)*52 + c0) = a1;
            *(float4*)(Xs + (r0+2)*52 + c0) = a2;
            *(float4*)(Xs + (r0+3)*52 + c0) = a3;
        } else if (tid >= 192 && tid < 240) {
            const int c = tid - 192;
            float acc = qtc[c];
            #pragma unroll
            for (int k = 0; k < 32; ++k) acc += Fs[k*52 + c] * wv[k];
            qtc[c] = acc;
            if (c >= 32) Xs[c*52 + 48] = acc;   // qu into augmented col 48
        }
        BAR();

        // ========== G0..G3: block Gauss-Jordan on rows 32..47 of Xs:
        // [Qux (cols 0..31) | Quu (32..47) | qu (48)], uniform stride 52.
        // After G3: Wb cols 0..31 = KK = Quu^-1 Qux, col 48 = kk.
        float* Kbase = Kws + (size_t)(b*TT + t) * 528;
        #pragma unroll
        for (int q = 0; q < 4; ++q) {
            const float* S = (q == 0) ? (Xs + 32*52) : ((q & 1) ? Wa : Wb);
            float*       D = (q & 1) ? Wb : Wa;
            const int pc = 4*q;

            float4 pr[4];
            #pragma unroll
            for (int m = 0; m < 4; ++m)
                pr[m] = *(const float4*)(S + (4*q + m)*52 + 32 + pc);
            float IP[4][4];
            inv4(pr, IP);

            if (tid < 196) {
                const int c  = tid >> 2;      // 0..48
                const int rg = tid & 3;       // row group
                float sn[4], R[4];
                #pragma unroll
                for (int n = 0; n < 4; ++n) sn[n] = S[(4*q + n)*52 + c];
                #pragma unroll
                for (int m = 0; m < 4; ++m)
                    R[m] = IP[m][0]*sn[0] + IP[m][1]*sn[1] + IP[m][2]*sn[2] + IP[m][3]*sn[3];

                #pragma unroll
                for (int i2 = 0; i2 < 4; ++i2) {
                    const int r = 4*rg + i2;
                    float val;
                    if (rg == q) {
                        val = R[i2];
                    } else {
                        float4 f = *(const float4*)(S + r*52 + 32 + pc);
                        float src = S[r*52 + c];
                        val = src - (f.x*R[0] + f.y*R[1] + f.z*R[2] + f.w*R[3]);
                    }
                    D[r*52 + c] = val;
                    if (q == 3) {
                        if (c < 32)       Kbase[c*16 + r] = -val;  // KT[state][ctrl]
                        else if (c == 48) Kbase[512 + r]  = -val;  // k[ctrl]
                    }
                }
            }
            BAR();
        }

        // ========== P7: V' = Qxx' - Qxu'*KK (direct, into Vs) ; v' = qx' - Qxu'*kk
        {
            const int i = tid >> 3, j0 = (tid & 7) * 4;
            float4 acc = *(const float4*)(Xs + i*52 + j0);
            float qxu[16];
            #pragma unroll
            for (int m = 0; m < 4; ++m) {
                float4 v4 = *(const float4*)(Xs + i*52 + 32 + m*4);
                qxu[m*4+0] = v4.x; qxu[m*4+1] = v4.y;
                qxu[m*4+2] = v4.z; qxu[m*4+3] = v4.w;
            }
            #pragma unroll
            for (int k = 0; k < 16; ++k) {
                float4 kk = *(const float4*)(Wb + k*52 + j0);
                acc.x -= qxu[k]*kk.x; acc.y -= qxu[k]*kk.y;
                acc.z -= qxu[k]*kk.z; acc.w -= qxu[k]*kk.w;
            }
            *(float4*)(Vs + i*36 + j0) = acc;
            if ((tid & 7) == 0) {
                float accv = qtc[i];
                #pragma unroll
                for (int k = 0; k < 16; ++k)
                    accv -= qxu[k] * Wb[k*52 + 48];
                vsv[i] = accv;
            }
        }
        BARV();   // drains this step's prefetch loads + K stores
    }
}

// ---------------------------------------------------------------------------
// Forward rollout, one wave per batch, register-prefetched K.
// ---------------------------------------------------------------------------
__global__ __launch_bounds__(64, 1)
void lqr_forward(const float* __restrict__ Kws, const float* __restrict__ A,
                 const float* __restrict__ Bm, const float* __restrict__ c1,
                 const float* __restrict__ x_init,
                 float* __restrict__ xs, float* __restrict__ us,
                 float* __restrict__ taus)
{
    const int b = blockIdx.x, l = threadIdx.x;
    __shared__ __align__(16) float Fb[32*48];
    __shared__ __align__(16) float Kb[544];
    __shared__ float c1s[32], xu[48];

    for (int s = l; s < 256; s += 64) {
        int k = s >> 3, q = s & 7;
        ((float4*)Fb)[k*12 + q] = ((const float4*)A)[(b*32 + k)*8 + q];
    }
    for (int s = l; s < 128; s += 64) {
        int k = s >> 2, q = s & 3;
        ((float4*)Fb)[k*12 + 8 + q] = ((const float4*)Bm)[(b*32 + k)*4 + q];
    }
    if (l < 32) { c1s[l] = c1[b*32 + l]; xu[l] = x_init[b*32 + l]; }

    // preload K[0]
    float4 ka, kb, kc = make_float4(0,0,0,0);
    {
        const float4* s0 = (const float4*)(Kws + (size_t)(b*TT) * 528);
        ka = s0[l]; kb = s0[l + 64];
        if (l < 4) kc = s0[l + 128];
    }
    __syncthreads();

    for (int t = 0; t < TT; ++t) {
        ((float4*)Kb)[l]      = ka;
        ((float4*)Kb)[l + 64] = kb;
        if (l < 4) ((float4*)Kb)[l + 128] = kc;
        __syncthreads();

        // prefetch K[t+1] (consumed at next iteration's Kb write)
        if (t + 1 < TT) {
            const float4* sn = (const float4*)(Kws + (size_t)(b*TT + t+1) * 528);
            ka = sn[l]; kb = sn[l + 64];
            if (l < 4) kc = sn[l + 128];
        }

        // u = K x + k   (KT stored as [j][i])
        float part = 0.0f;
        int i = l & 15, g = l >> 4;
        #pragma unroll
        for (int jj = 0; jj < 8; ++jj) {
            int j = g*8 + jj;
            part += Kb[j*16 + i] * xu[j];
        }
        part += __shfl_down(part, 32);
        part += __shfl_down(part, 16);
        float ui = part + Kb[512 + i];
        if (l < 16) {
            xu[32 + l] = ui;
            us[(size_t)(t*64 + b)*16 + l] = ui;
        }
        __syncthreads();

        if (l < 32) xs[(size_t)(t*64 + b)*32 + l] = xu[l];
        if (l < 48) taus[(size_t)(t*64 + b)*48 + l] = xu[l];

        // xn = F xu + c1
        float pn = 0.0f;
        int i2 = l & 31, h = l >> 5;
        #pragma unroll
        for (int jj = 0; jj < 24; ++jj) {
            int j = h*24 + jj;
            pn += Fb[i2*48 + j] * xu[j];
        }
        pn += __shfl_down(pn, 32);
        float xni = pn + ((l < 32) ? c1s[i2] : 0.0f);
        __syncthreads();
        if (l < 32) xu[l] = xni;
        __syncthreads();
    }
}

// ---------------------------------------------------------------------------
// objs[t,b] = 0.5*xu^T Q xu + xu.p   (fully parallel, mem-bound)
// ---------------------------------------------------------------------------
__global__ __launch_bounds__(256, 4)
void lqr_obj(const float* __restrict__ Q, const float* __restrict__ p,
             const float* __restrict__ taus, float* __restrict__ objs)
{
    const int bi = blockIdx.x;            // = b*T + t
    const int b = bi >> 7, t = bi & 127;
    const int tid = threadIdx.x;
    __shared__ float xu[48];
    __shared__ float red[8];
    const float* tp = taus + (size_t)(t*64 + b)*48;
    if (tid < 48) xu[tid] = tp[tid];
    __syncthreads();

    const float4* Q4 = (const float4*)(Q + (size_t)bi * 2304);
    float acc = 0.0f;
    for (int e4 = tid; e4 < 576; e4 += 256) {
        float4 qv = Q4[e4];
        int r = e4 / 12, c = (e4 % 12) * 4;
        float xr = xu[r];
        acc += xr * (qv.x*xu[c] + qv.y*xu[c+1] + qv.z*xu[c+2] + qv.w*xu[c+3]);
    }
    acc *= 0.5f;
    if (tid < 48) acc += xu[tid] * p[(size_t)bi*48 + tid];

    #pragma unroll
    for (int off = 32; off > 0; off >>= 1) acc += __shfl_down(acc, off);
    if ((tid & 63) == 0) red[tid >> 6] = acc;
    __syncthreads();
    if (tid == 0) objs[(t << 6) + b] = red[0] + red[1] + red[2] + red[3];
}

// ---------------------------------------------------------------------------
extern "C" void kernel_launch(void* const* d_in, const int* in_sizes, int n_in,
                              void* d_out, int out_size, void* d_ws, size_t ws_size,
                              hipStream_t stream) {
    const float* x_init = (const float*)d_in[0];
    const float* Q      = (const float*)d_in[1];
    const float* p      = (const float*)d_in[2];
    const float* A      = (const float*)d_in[3];
    const float* Bm     = (const float*)d_in[4];
    const float* c1     = (const float*)d_in[5];

    float* out  = (float*)d_out;
    float* xs   = out;                       // 128*64*32 = 262144
    float* us   = out + 262144;              // 128*64*16 = 131072
    float* objs = out + 393216;              // 128*64    = 8192
    float* taus = out + 401408;              // 128*64*48 = 393216

    float* Kws = (float*)d_ws;               // 64*128*528 floats = 17.3 MB

    lqr_backward<<<NBATCH, 256, 0, stream>>>(Q, p, A, Bm, c1, Kws);
    lqr_forward<<<NBATCH, 64, 0, stream>>>(Kws, A, Bm, c1, x_init, xs, us, taus);
    lqr_obj<<<NBATCH*TT, 256, 0, stream>>>(Q, p, taus, objs);
}